// Round 1
// baseline (346.868 us; speedup 1.0000x reference)
//
#include <hip/hip_runtime.h>
#include <math.h>

// Problem constants (fixed by reference).
#define TOKENS      16384     // 8 * 2048
#define HID         2048
#define EXPERTS     64
#define CAPSLOT     1024      // per-expert list cap; counts ~Binom(16384,1/64)=256±16
#define CAP         512       // expert_capacity = 2*ceil(16384/64)

__device__ __forceinline__ void fma8(float* a, float s, float4 w0, float4 w1) {
    a[0] = fmaf(s, w0.x, a[0]); a[1] = fmaf(s, w0.y, a[1]);
    a[2] = fmaf(s, w0.z, a[2]); a[3] = fmaf(s, w0.w, a[3]);
    a[4] = fmaf(s, w1.x, a[4]); a[5] = fmaf(s, w1.y, a[5]);
    a[6] = fmaf(s, w1.z, a[6]); a[7] = fmaf(s, w1.w, a[7]);
}

// ---------------------------------------------------------------------------
// K1: fused logits GEMM + softmax + top1/top2 routing.
// Grid = 512 blocks x 512 threads (8 waves) -> 2 blocks/CU, 16 waves/CU,
// 4 waves/SIMD (launch_bounds caps VGPR at 128). Block owns 32 tokens, full K.
// Wave w computes k-chunk [w*256, w*256+256) for 32 tokens x 64 experts
// (thread tile: 4 tokens x 8 experts = 32 fp32 acc; per k4-step 128 FMA for
// 12 float4 loads). x read exactly once from HBM; W (512 KB, L2-resident)
// streamed once per wave -- no LDS staging, no staging barrier.
// Then a 3-barrier LDS tree (32 KB) reduces the 8 chunk-partials
// deterministically, and wave 0 routes its 32 tokens fully in-register
// (8-lane shfl_xor butterflies), writing p1/p2/top1/top2.
// Eliminates the global partial buffer (16.8 MB RT) and the k_route kernel.
// ---------------------------------------------------------------------------
__global__ __launch_bounds__(512, 4) void k_gemm_route(
    const float* __restrict__ x, const float* __restrict__ W,
    float* __restrict__ p1o, float* __restrict__ p2o,
    int* __restrict__ top1o, int* __restrict__ top2o)
{
    __shared__ float red[4 * 2048];   // 4 slots x 8 KB = 32 KB

    const int tid  = threadIdx.x;
    const int w    = tid >> 6;        // wave index 0..7 == k-chunk
    const int lane = tid & 63;
    const int tg   = lane >> 3;       // token group 0..7 (4 tokens each)
    const int eg   = lane & 7;        // expert group 0..7 (8 experts each)
    const int tok0 = blockIdx.x * 32;

    const float* xb = x + (size_t)(tok0 + tg * 4) * HID + w * 256;
    const float* wb = W + (size_t)(w * 256) * EXPERTS + eg * 8;

    float acc[4][8];
    #pragma unroll
    for (int i = 0; i < 4; ++i)
        #pragma unroll
        for (int j = 0; j < 8; ++j) acc[i][j] = 0.f;

    // ---- GEMM over this wave's 256-wide k-chunk ----
    for (int k4 = 0; k4 < 256; k4 += 4) {
        float4 xv[4];
        #pragma unroll
        for (int i = 0; i < 4; ++i)
            xv[i] = *(const float4*)(xb + (size_t)i * HID + k4);

        float4 w0[4], w1[4];
        #pragma unroll
        for (int kk = 0; kk < 4; ++kk) {
            const float* wp = wb + (size_t)(k4 + kk) * EXPERTS;
            w0[kk] = *(const float4*)wp;
            w1[kk] = *(const float4*)(wp + 4);
        }

        #pragma unroll
        for (int i = 0; i < 4; ++i) {
            fma8(acc[i], xv[i].x, w0[0], w1[0]);
            fma8(acc[i], xv[i].y, w0[1], w1[1]);
            fma8(acc[i], xv[i].z, w0[2], w1[2]);
            fma8(acc[i], xv[i].w, w0[3], w1[3]);
        }
    }

    // ---- deterministic tree reduction over the 8 chunk-waves ----
    // Layout per slot: float4 q (0..7) at [q*256 + lane*4] -> consecutive
    // 16 B per lane, conflict-free b128 pattern.
    auto WR = [&](int slot) {
        float* b = red + slot * 2048 + lane * 4;
        #pragma unroll
        for (int q = 0; q < 8; ++q) {
            const int i = q >> 1, j0 = (q & 1) * 4;
            *(float4*)(b + q * 256) = make_float4(
                acc[i][j0 + 0], acc[i][j0 + 1], acc[i][j0 + 2], acc[i][j0 + 3]);
        }
    };
    auto AD = [&](int slot) {
        const float* b = red + slot * 2048 + lane * 4;
        #pragma unroll
        for (int q = 0; q < 8; ++q) {
            const int i = q >> 1, j0 = (q & 1) * 4;
            float4 r = *(const float4*)(b + q * 256);
            acc[i][j0 + 0] += r.x; acc[i][j0 + 1] += r.y;
            acc[i][j0 + 2] += r.z; acc[i][j0 + 3] += r.w;
        }
    };

    if (w >= 4) WR(w - 4);                       // waves 4..7 -> slots 0..3
    __syncthreads();
    if (w < 4) { AD(w); if (w >= 2) WR(w); }     // 0..3 add; 2,3 re-write own slot
    __syncthreads();
    if (w < 2) { AD(w + 2); if (w == 1) WR(1); } // 0,1 add; 1 re-writes slot 1
    __syncthreads();

    if (w == 0) {
        AD(1);  // wave 0 now holds final logits for its 32 tokens

        // ---- fused route: per token, over 8 eg-lanes x 8 in-lane values ----
        #pragma unroll
        for (int i = 0; i < 4; ++i) {
            // top-1 argmax, first-index tie-break
            float bv = acc[i][0]; int be = eg * 8;
            #pragma unroll
            for (int j = 1; j < 8; ++j)
                if (acc[i][j] > bv) { bv = acc[i][j]; be = eg * 8 + j; }
            #pragma unroll
            for (int m = 1; m <= 4; m <<= 1) {
                float ov = __shfl_xor(bv, m);
                int   oe = __shfl_xor(be, m);
                if (ov > bv || (ov == bv && oe < be)) { bv = ov; be = oe; }
            }
            const float m1 = bv;
            const int   e1 = be;

            // top-2: argmax excluding e1
            float bv2 = -INFINITY; int be2 = 1 << 30;
            #pragma unroll
            for (int j = 0; j < 8; ++j) {
                const int e = eg * 8 + j;
                if (e != e1 && acc[i][j] > bv2) { bv2 = acc[i][j]; be2 = e; }
            }
            #pragma unroll
            for (int m = 1; m <= 4; m <<= 1) {
                float ov = __shfl_xor(bv2, m);
                int   oe = __shfl_xor(be2, m);
                if (ov > bv2 || (ov == bv2 && oe < be2)) { bv2 = ov; be2 = oe; }
            }

            // softmax denominator (max-subtracted)
            float s = 0.f;
            #pragma unroll
            for (int j = 0; j < 8; ++j) s += expf(acc[i][j] - m1);
            #pragma unroll
            for (int m = 1; m <= 4; m <<= 1) s += __shfl_xor(s, m);

            if (eg == 0) {
                const int t = tok0 + tg * 4 + i;
                p1o[t]   = 1.0f / s;
                p2o[t]   = expf(bv2 - m1) / s;
                top1o[t] = e1;
                top2o[t] = be2;
            }
        }
    }
}

// ---------------------------------------------------------------------------
// K2: per-expert batch-prioritized ranking -> keep flags. One block per
// expert scans ALL tokens (top1/p1 are 128 KB total -> L2/L1-hot; the 64x
// redundancy is cheap), builds its list in LDS with block-local atomics
// (no cross-block contention), then O(n^2) rank.
// rank(t) = #{t' in same list : p1[t'] > p1[t] or (== and t' < t)}
// keep1: rank1 < CAP.  keep2: rank2 + n1_raw (pre-drop top1 count) < CAP.
// ---------------------------------------------------------------------------
__global__ __launch_bounds__(256) void k_rank(
    const float* __restrict__ p1,
    const int* __restrict__ top1, const int* __restrict__ top2,
    int* __restrict__ keep1, int* __restrict__ keep2)
{
    __shared__ float skey[CAPSLOT];
    __shared__ int   stok[CAPSLOT];
    __shared__ int   cnt;

    const int e   = blockIdx.x;
    const int tid = threadIdx.x;

    // ---- scan for top-1 == e ----
    if (tid == 0) cnt = 0;
    __syncthreads();
    for (int t = tid; t < TOKENS; t += 256) {
        if (top1[t] == e) {
            int i = atomicAdd(&cnt, 1);
            if (i < CAPSLOT) { stok[i] = t; skey[i] = p1[t]; }
        }
    }
    __syncthreads();
    const int n1_raw = cnt;
    const int n1 = min(n1_raw, CAPSLOT);

    for (int i = tid; i < n1; i += 256) {
        const float ki = skey[i];
        const int   ti = stok[i];
        int r = 0;
        for (int j = 0; j < n1; ++j)
            r += (skey[j] > ki || (skey[j] == ki && stok[j] < ti)) ? 1 : 0;
        keep1[ti] = (r < CAP) ? 1 : 0;
    }
    __syncthreads();

    // ---- scan for top-2 == e ----
    if (tid == 0) cnt = 0;
    __syncthreads();
    for (int t = tid; t < TOKENS; t += 256) {
        if (top2[t] == e) {
            int i = atomicAdd(&cnt, 1);
            if (i < CAPSLOT) { stok[i] = t; skey[i] = p1[t]; }
        }
    }
    __syncthreads();
    const int n2 = min(cnt, CAPSLOT);

    for (int i = tid; i < n2; i += 256) {
        const float ki = skey[i];
        const int   ti = stok[i];
        int r = n1_raw;                    // offset by pre-drop top-1 count
        for (int j = 0; j < n2; ++j)
            r += (skey[j] > ki || (skey[j] == ki && stok[j] < ti)) ? 1 : 0;
        keep2[ti] = (r < CAP) ? 1 : 0;
    }
}

// ---------------------------------------------------------------------------
// K3: materialize [top_1_mask | gates], coalesced (16 threads per token row).
// ---------------------------------------------------------------------------
__global__ __launch_bounds__(256) void k_out(
    const float* __restrict__ p1, const float* __restrict__ p2,
    const int* __restrict__ top1, const int* __restrict__ top2,
    const int* __restrict__ keep1, const int* __restrict__ keep2,
    float* __restrict__ out)
{
    const int tid   = threadIdx.x;
    const int token = blockIdx.x * 16 + (tid >> 4);
    const int eb    = (tid & 15) * 4;

    const int  k1 = keep1[token];
    const int  k2 = keep2[token];
    const float P1 = k1 ? p1[token] : 0.0f;
    const float P2 = k2 ? p2[token] : 0.0f;
    const float denom = fmaxf(P1 + P2, 1.1920929e-07f);   // fp32 eps clip
    const float g1 = P1 / denom;
    const float g2 = P2 / denom;
    const int e1 = top1[token];
    const int e2 = top2[token];

    float4 mv, pv;
    mv.x = (k1 && e1 == eb + 0) ? 1.0f : 0.0f;
    mv.y = (k1 && e1 == eb + 1) ? 1.0f : 0.0f;
    mv.z = (k1 && e1 == eb + 2) ? 1.0f : 0.0f;
    mv.w = (k1 && e1 == eb + 3) ? 1.0f : 0.0f;
    pv.x = (k1 && e1 == eb + 0) ? g1 : ((k2 && e2 == eb + 0) ? g2 : 0.0f);
    pv.y = (k1 && e1 == eb + 1) ? g1 : ((k2 && e2 == eb + 1) ? g2 : 0.0f);
    pv.z = (k1 && e1 == eb + 2) ? g1 : ((k2 && e2 == eb + 2) ? g2 : 0.0f);
    pv.w = (k1 && e1 == eb + 3) ? g1 : ((k2 && e2 == eb + 3) ? g2 : 0.0f);

    *(float4*)(out + (size_t)token * EXPERTS + eb) = mv;
    *(float4*)(out + (size_t)TOKENS * EXPERTS + (size_t)token * EXPERTS + eb) = pv;
}

// ---------------------------------------------------------------------------
extern "C" void kernel_launch(void* const* d_in, const int* in_sizes, int n_in,
                              void* d_out, int out_size, void* d_ws, size_t ws_size,
                              hipStream_t stream)
{
    const float* x = (const float*)d_in[0];   // (8,2048,2048) fp32
    const float* W = (const float*)d_in[1];   // (2048,64) fp32
    float* out = (float*)d_out;               // 2 * 16384 * 64 fp32

    // workspace layout (~0.4 MB)
    float* p1    = (float*)d_ws;
    float* p2    = p1 + TOKENS;
    int*   top1  = (int*)(p2 + TOKENS);
    int*   top2  = top1 + TOKENS;
    int*   keep1 = top2 + TOKENS;
    int*   keep2 = keep1 + TOKENS;

    k_gemm_route<<<512, 512, 0, stream>>>(x, W, p1, p2, top1, top2);
    k_rank<<<EXPERTS, 256, 0, stream>>>(p1, top1, top2, keep1, keep2);
    k_out<<<TOKENS / 16, 256, 0, stream>>>(
        p1, p2, top1, top2, keep1, keep2, out);
}